// Round 8
// baseline (3534.501 us; speedup 1.0000x reference)
//
#include <hip/hip_runtime.h>
#include <hip/hip_bf16.h>

#define BB 8
#define NN 2048
#define FIN 512
#define FOUT 256
#define EE 5
#define ALPHA_ 0.2f
#define NEGV -9e15f
#define JW 512    // j-window per jz
#define LDA 40    // padded LDS stride for 32-col tiles
#define LDH 72    // padded LDS stride for 64-col tiles
#define LDP 132   // padded LDS stride for P staging (128 cols)

typedef __hip_bfloat16 bf16;
typedef __bf16 bf16x8 __attribute__((ext_vector_type(8)));
typedef float f32x4 __attribute__((ext_vector_type(4)));
typedef unsigned long long u64;

__device__ __forceinline__ float bf2f(bf16 x) { return __bfloat162float(x); }
__device__ __forceinline__ bf16 f2bf(float x) { return __float2bfloat16(x); }

// ---------------- split fp32 -> bf16 (hi, lo), flat, 8/thread ----------------
__global__ void split_f32_bf16(const float* __restrict__ in,
                               bf16* __restrict__ hi, bf16* __restrict__ lo) {
    long i = ((long)blockIdx.x * blockDim.x + threadIdx.x) * 8;
    float4 a = *(const float4*)(&in[i]);
    float4 b = *(const float4*)(&in[i + 4]);
    float x[8] = { a.x, a.y, a.z, a.w, b.x, b.y, b.z, b.w };
    bf16 th[8], tl[8];
    for (int k = 0; k < 8; k++) {
        th[k] = f2bf(x[k]);
        tl[k] = f2bf(x[k] - bf2f(th[k]));
    }
    *(uint4*)(&hi[i]) = *(const uint4*)th;
    *(uint4*)(&lo[i]) = *(const uint4*)tl;
}

// ---------------- pack adj (int32 > 0) into 64-col bitmasks ----------------
__global__ void pack_adj(const int* __restrict__ adj, u64* __restrict__ adjm) {
    long wid = (((long)blockIdx.x * 256) + threadIdx.x) >> 6;
    int lane = threadIdx.x & 63;
    long base = wid * 256;
    for (int c = 0; c < 4; c++) {
        int a = adj[base + c * 64 + lane];
        u64 m = __ballot(a > 0);
        if (lane == 0) adjm[base / 64 + c] = m;
    }
}

// ---------------- transpose+split: fp32 [R,C] -> bf16 hi/lo [C,R] ----------------
__global__ void transpose_split(const float* __restrict__ in,
                                bf16* __restrict__ hi, bf16* __restrict__ lo,
                                int R, int C) {
    __shared__ bf16 th[32][33], tl[32][33];
    int c0 = blockIdx.x * 32, r0 = blockIdx.y * 32;
    int x = threadIdx.x, y = threadIdx.y;  // 32 x 8
    for (int k = 0; k < 4; k++) {
        int r = y + k * 8;
        float f = in[(long)(r0 + r) * C + c0 + x];
        bf16 h = f2bf(f);
        th[r][x] = h;
        tl[r][x] = f2bf(f - bf2f(h));
    }
    __syncthreads();
    for (int k = 0; k < 4; k++) {
        int r = y + k * 8;
        hi[(long)(c0 + r) * R + r0 + x] = th[x][r];
        lo[(long)(c0 + r) * R + r0 + x] = tl[x][r];
    }
}

// ---------------- transpose + convert: fp32 [R,C] -> bf16 [C,R] ----------------
__global__ void transpose_f32_bf16(const float* __restrict__ in, bf16* __restrict__ out,
                                   int R, int C, long sin_b, long sout_b) {
    __shared__ bf16 tile[32][33];
    long bi = (long)blockIdx.z * sin_b;
    long bo = (long)blockIdx.z * sout_b;
    int c0 = blockIdx.x * 32, r0 = blockIdx.y * 32;
    int x = threadIdx.x, y = threadIdx.y;
    for (int k = 0; k < 4; k++) {
        int r = y + k * 8;
        tile[r][x] = f2bf(in[bi + (long)(r0 + r) * C + c0 + x]);
    }
    __syncthreads();
    for (int k = 0; k < 4; k++) {
        int r = y + k * 8;
        out[bo + (long)(c0 + r) * R + r0 + x] = tile[x][r];
    }
}

// ---------------- split GEMM: C = (Ah+Al)[M,K] @ (Bh+Bl)[N,K]^T + bias ----------------
__global__ __launch_bounds__(256) void gemm_bt_split(
        const bf16* __restrict__ Ah, const bf16* __restrict__ Al,
        const bf16* __restrict__ Bh, const bf16* __restrict__ Bl,
        bf16* __restrict__ Chi, bf16* __restrict__ Clo,
        const float* __restrict__ bias, int Nn, int K) {
    __shared__ alignas(16) bf16 Ash[128 * LDA], Asl[128 * LDA];
    __shared__ alignas(16) bf16 Bsh[128 * LDA], Bsl[128 * LDA];
    int tid = threadIdx.x;
    int lane = tid & 63, ww = tid >> 6;
    int wm = ww >> 1, wn = ww & 1;
    int quad = lane >> 4, l16 = lane & 15;
    int m0 = blockIdx.x * 128, n0 = blockIdx.y * 128;
    f32x4 acc[4][4] = {};
    for (int k0 = 0; k0 < K; k0 += 32) {
        for (int i = 0; i < 2; i++) {
            int idx = tid + i * 256;
            int row = idx >> 2, seg = idx & 3;
            long ao = (long)(m0 + row) * K + k0 + seg * 8;
            long bo = (long)(n0 + row) * K + k0 + seg * 8;
            int so = row * LDA + seg * 8;
            *(uint4*)(&Ash[so]) = *(const uint4*)(&Ah[ao]);
            *(uint4*)(&Asl[so]) = *(const uint4*)(&Al[ao]);
            *(uint4*)(&Bsh[so]) = *(const uint4*)(&Bh[bo]);
            *(uint4*)(&Bsl[so]) = *(const uint4*)(&Bl[bo]);
        }
        __syncthreads();
        bf16x8 afh[4], afl[4], bfh[4], bfl[4];
        for (int mi = 0; mi < 4; mi++) {
            int so = (wm * 64 + mi * 16 + l16) * LDA + quad * 8;
            afh[mi] = *(const bf16x8*)(&Ash[so]);
            afl[mi] = *(const bf16x8*)(&Asl[so]);
        }
        for (int ni = 0; ni < 4; ni++) {
            int so = (wn * 64 + ni * 16 + l16) * LDA + quad * 8;
            bfh[ni] = *(const bf16x8*)(&Bsh[so]);
            bfl[ni] = *(const bf16x8*)(&Bsl[so]);
        }
        for (int mi = 0; mi < 4; mi++)
            for (int ni = 0; ni < 4; ni++) {
                acc[mi][ni] = __builtin_amdgcn_mfma_f32_16x16x32_bf16(afh[mi], bfh[ni], acc[mi][ni], 0, 0, 0);
                acc[mi][ni] = __builtin_amdgcn_mfma_f32_16x16x32_bf16(afh[mi], bfl[ni], acc[mi][ni], 0, 0, 0);
                acc[mi][ni] = __builtin_amdgcn_mfma_f32_16x16x32_bf16(afl[mi], bfh[ni], acc[mi][ni], 0, 0, 0);
            }
        __syncthreads();
    }
    for (int mi = 0; mi < 4; mi++)
        for (int ni = 0; ni < 4; ni++) {
            int col = n0 + wn * 64 + ni * 16 + l16;
            float bv = bias ? bias[col] : 0.f;
            for (int r = 0; r < 4; r++) {
                int row = m0 + wm * 64 + mi * 16 + quad * 4 + r;
                float v = acc[mi][ni][r] + bv;
                bf16 h = f2bf(v);
                Chi[(long)row * Nn + col] = h;
                Clo[(long)row * Nn + col] = f2bf(v - bf2f(h));
            }
        }
}

// ---------------- plain bf16 GEMM: C[M,N] = A[M,K] @ Bt[N,K]^T ----------------
__global__ __launch_bounds__(256) void gemm_bt(
        const bf16* __restrict__ A, const bf16* __restrict__ Bt,
        bf16* __restrict__ C, int Nn, int K, long sA, long sB, long sC) {
    __shared__ alignas(16) bf16 As[128 * LDA];
    __shared__ alignas(16) bf16 Bs[128 * LDA];
    const bf16* Ab = A + (long)blockIdx.z * sA;
    const bf16* Bb = Bt + (long)blockIdx.z * sB;
    bf16* Cb = C + (long)blockIdx.z * sC;
    int tid = threadIdx.x;
    int lane = tid & 63, ww = tid >> 6;
    int wm = ww >> 1, wn = ww & 1;
    int quad = lane >> 4, l16 = lane & 15;
    int m0 = blockIdx.x * 128, n0 = blockIdx.y * 128;
    f32x4 acc[4][4] = {};
    for (int k0 = 0; k0 < K; k0 += 32) {
        for (int i = 0; i < 2; i++) {
            int idx = tid + i * 256;
            int row = idx >> 2, seg = idx & 3;
            int so = row * LDA + seg * 8;
            *(uint4*)(&As[so]) =
                *(const uint4*)(&Ab[(long)(m0 + row) * K + k0 + seg * 8]);
            *(uint4*)(&Bs[so]) =
                *(const uint4*)(&Bb[(long)(n0 + row) * K + k0 + seg * 8]);
        }
        __syncthreads();
        bf16x8 af[4], bfr[4];
        for (int mi = 0; mi < 4; mi++)
            af[mi] = *(const bf16x8*)(&As[(wm * 64 + mi * 16 + l16) * LDA + quad * 8]);
        for (int ni = 0; ni < 4; ni++)
            bfr[ni] = *(const bf16x8*)(&Bs[(wn * 64 + ni * 16 + l16) * LDA + quad * 8]);
        for (int mi = 0; mi < 4; mi++)
            for (int ni = 0; ni < 4; ni++)
                acc[mi][ni] = __builtin_amdgcn_mfma_f32_16x16x32_bf16(
                    af[mi], bfr[ni], acc[mi][ni], 0, 0, 0);
        __syncthreads();
    }
    for (int mi = 0; mi < 4; mi++)
        for (int ni = 0; ni < 4; ni++) {
            int col = n0 + wn * 64 + ni * 16 + l16;
            for (int r = 0; r < 4; r++) {
                int row = m0 + wm * 64 + mi * 16 + quad * 4 + r;
                Cb[(long)row * Nn + col] = f2bf(acc[mi][ni][r]);
            }
        }
}

// ---------------- Ay[b,n] = (hh+hl)[b,n,:] . a2 ----------------
__global__ void ay_kernel(const bf16* __restrict__ hh, const bf16* __restrict__ hl,
                          const float* __restrict__ a2, float* __restrict__ Ay) {
    int lane = threadIdx.x & 63, w = threadIdx.x >> 6;
    long row = (long)blockIdx.x * 4 + w;
    float p = 0.f;
    for (int i = 0; i < 4; i++) {
        int d = i * 64 + lane;
        p += (bf2f(hh[row * FOUT + d]) + bf2f(hl[row * FOUT + d])) * a2[d];
    }
    for (int off = 32; off; off >>= 1) p += __shfl_xor(p, off);
    if (lane == 0) Ay[row] = p;
}

// ---------------- pass 1: partial softmax stats over a 512-j window ----------------
// Block = 4 waves, 64 i-rows; j-window 512. h staged in padded LDS (128x64 per
// stage, stride LDH=72 -> conflict-free); split scores; online m/l; partials out.
__global__ __launch_bounds__(256) void pass1_ml(
        const bf16* __restrict__ qh_, const bf16* __restrict__ ql_,
        const bf16* __restrict__ hh_, const bf16* __restrict__ hl_,
        const u64* __restrict__ adjm, const float* __restrict__ Ay,
        float2* __restrict__ mlpart) {
    __shared__ alignas(16) bf16 Hsh[128 * LDH], Hsl[128 * LDH];
    int tid = threadIdx.x;
    int lane = tid & 63, w = tid >> 6;
    int quad = lane >> 4, l16 = lane & 15;
    int b = blockIdx.z, jz = blockIdx.y;
    int i0 = blockIdx.x * 64 + w * 16;
    long qoff = ((long)b * NN + i0) * FOUT;
    const bf16* hbh = hh_ + ((long)b * NN + (long)jz * JW) * FOUT;
    const bf16* hbl = hl_ + ((long)b * NN + (long)jz * JW) * FOUT;
    const u64* amb = adjm + ((long)b * NN + i0) * (NN / 64) + jz * (JW / 64);

    bf16x8 qfh[8], qfl[8];
#pragma unroll
    for (int kk = 0; kk < 8; kk++) {
        qfh[kk] = *(const bf16x8*)(&qh_[qoff + (long)l16 * FOUT + kk * 32 + quad * 8]);
        qfl[kk] = *(const bf16x8*)(&ql_[qoff + (long)l16 * FOUT + kk * 32 + quad * 8]);
    }
    float ay_[4];
#pragma unroll
    for (int r = 0; r < 4; r++) ay_[r] = Ay[(long)b * NN + i0 + quad * 4 + r];

    float m_[4], l_[4];
#pragma unroll
    for (int r = 0; r < 4; r++) { m_[r] = -3.0e38f; l_[r] = 0.f; }

    for (int jc = 0; jc < JW / 128; jc++) {
        f32x4 sacc[8] = {};
        for (int kh = 0; kh < 4; kh++) {          // 64-col K stages
            __syncthreads();
#pragma unroll
            for (int i = 0; i < 4; i++) {
                int idx = tid + i * 256;          // 1024 segs of 8
                int row = idx >> 3, seg = idx & 7;
                long go = (long)(jc * 128 + row) * FOUT + kh * 64 + seg * 8;
                int so = row * LDH + seg * 8;
                *(uint4*)(&Hsh[so]) = *(const uint4*)(&hbh[go]);
                *(uint4*)(&Hsl[so]) = *(const uint4*)(&hbl[go]);
            }
            __syncthreads();
#pragma unroll
            for (int k2 = 0; k2 < 2; k2++) {
                int kk = kh * 2 + k2;
#pragma unroll
                for (int ni = 0; ni < 8; ni++) {
                    int so = (ni * 16 + l16) * LDH + k2 * 32 + quad * 8;
                    bf16x8 hfh = *(const bf16x8*)(&Hsh[so]);
                    bf16x8 hfl = *(const bf16x8*)(&Hsl[so]);
                    sacc[ni] = __builtin_amdgcn_mfma_f32_16x16x32_bf16(qfh[kk], hfh, sacc[ni], 0, 0, 0);
                    sacc[ni] = __builtin_amdgcn_mfma_f32_16x16x32_bf16(qfh[kk], hfl, sacc[ni], 0, 0, 0);
                    sacc[ni] = __builtin_amdgcn_mfma_f32_16x16x32_bf16(qfl[kk], hfh, sacc[ni], 0, 0, 0);
                }
            }
        }
        u64 am[4][2];
#pragma unroll
        for (int r = 0; r < 4; r++) {
            am[r][0] = amb[(long)(quad * 4 + r) * (NN / 64) + jc * 2 + 0];
            am[r][1] = amb[(long)(quad * 4 + r) * (NN / 64) + jc * 2 + 1];
        }
        // in-place leaky relu + mask
#pragma unroll
        for (int ni = 0; ni < 8; ni++)
#pragma unroll
            for (int r = 0; r < 4; r++) {
                float v = sacc[ni][r] + ay_[r];
                v = v > 0.f ? v : ALPHA_ * v;
                int bit = (int)((am[r][ni >> 2] >> ((ni * 16 + l16) & 63)) & 1);
                sacc[ni][r] = bit ? v : NEGV;
            }
#pragma unroll
        for (int r = 0; r < 4; r++) {
            float mc = -3.0e38f;
#pragma unroll
            for (int ni = 0; ni < 8; ni++) mc = fmaxf(mc, sacc[ni][r]);
            for (int off = 8; off; off >>= 1) mc = fmaxf(mc, __shfl_xor(mc, off));
            float mnew = fmaxf(m_[r], mc);
            float scale = __expf(m_[r] - mnew);
            float ps = 0.f;
#pragma unroll
            for (int ni = 0; ni < 8; ni++) ps += __expf(sacc[ni][r] - mnew);
            for (int off = 8; off; off >>= 1) ps += __shfl_xor(ps, off);
            l_[r] = l_[r] * scale + ps;
            m_[r] = mnew;
        }
    }
    if (l16 == 0) {
#pragma unroll
        for (int r = 0; r < 4; r++)
            mlpart[((long)b * 4 + jz) * NN + i0 + quad * 4 + r] =
                make_float2(m_[r], l_[r]);
    }
}

// ---------------- merge 4 window partials -> (m, 1/l) per row ----------------
__global__ void ml_merge(const float2* __restrict__ mlpart, float2* __restrict__ mlfin) {
    long row = (long)blockIdx.x * blockDim.x + threadIdx.x;  // [0, BB*NN)
    long b = row / NN, n = row % NN;
    float2 p[4];
    float m = -3.0e38f;
    for (int jz = 0; jz < 4; jz++) {
        p[jz] = mlpart[(b * 4 + jz) * NN + n];
        m = fmaxf(m, p[jz].x);
    }
    float l = 0.f;
    for (int jz = 0; jz < 4; jz++) l += p[jz].y * __expf(p[jz].x - m);
    mlfin[row] = make_float2(m, 1.f / l);
}

// ---------------- pass 2: recompute scores, write normalized P (bf16) ----------------
__global__ __launch_bounds__(256) void pass2_p(
        const bf16* __restrict__ qh_, const bf16* __restrict__ ql_,
        const bf16* __restrict__ hh_, const bf16* __restrict__ hl_,
        const u64* __restrict__ adjm, const float* __restrict__ Ay,
        const float2* __restrict__ mlfin, bf16* __restrict__ P, int b0) {
    __shared__ alignas(16) bf16 Hsh[128 * LDH], Hsl[128 * LDH];
    __shared__ alignas(16) bf16 pst[4][16 * LDP];   // dedicated: never aliases Hs
    int tid = threadIdx.x;
    int lane = tid & 63, w = tid >> 6;
    int quad = lane >> 4, l16 = lane & 15;
    int bz = blockIdx.z, b = b0 + bz, jz = blockIdx.y;
    int i0 = blockIdx.x * 64 + w * 16;
    long qoff = ((long)b * NN + i0) * FOUT;
    const bf16* hbh = hh_ + ((long)b * NN + (long)jz * JW) * FOUT;
    const bf16* hbl = hl_ + ((long)b * NN + (long)jz * JW) * FOUT;
    const u64* amb = adjm + ((long)b * NN + i0) * (NN / 64) + jz * (JW / 64);
    bf16* pw = pst[w];

    bf16x8 qfh[8], qfl[8];
#pragma unroll
    for (int kk = 0; kk < 8; kk++) {
        qfh[kk] = *(const bf16x8*)(&qh_[qoff + (long)l16 * FOUT + kk * 32 + quad * 8]);
        qfl[kk] = *(const bf16x8*)(&ql_[qoff + (long)l16 * FOUT + kk * 32 + quad * 8]);
    }
    float ay_[4], mrow[4], linv[4];
#pragma unroll
    for (int r = 0; r < 4; r++) {
        ay_[r] = Ay[(long)b * NN + i0 + quad * 4 + r];
        float2 t = mlfin[(long)b * NN + i0 + quad * 4 + r];
        mrow[r] = t.x;
        linv[r] = t.y;
    }

    for (int jc = 0; jc < JW / 128; jc++) {
        f32x4 sacc[8] = {};
        for (int kh = 0; kh < 4; kh++) {
            __syncthreads();
#pragma unroll
            for (int i = 0; i < 4; i++) {
                int idx = tid + i * 256;
                int row = idx >> 3, seg = idx & 7;
                long go = (long)(jc * 128 + row) * FOUT + kh * 64 + seg * 8;
                int so = row * LDH + seg * 8;
                *(uint4*)(&Hsh[so]) = *(const uint4*)(&hbh[go]);
                *(uint4*)(&Hsl[so]) = *(const uint4*)(&hbl[go]);
            }
            __syncthreads();
#pragma unroll
            for (int k2 = 0; k2 < 2; k2++) {
                int kk = kh * 2 + k2;
#pragma unroll
                for (int ni = 0; ni < 8; ni++) {
                    int so = (ni * 16 + l16) * LDH + k2 * 32 + quad * 8;
                    bf16x8 hfh = *(const bf16x8*)(&Hsh[so]);
                    bf16x8 hfl = *(const bf16x8*)(&Hsl[so]);
                    sacc[ni] = __builtin_amdgcn_mfma_f32_16x16x32_bf16(qfh[kk], hfh, sacc[ni], 0, 0, 0);
                    sacc[ni] = __builtin_amdgcn_mfma_f32_16x16x32_bf16(qfh[kk], hfl, sacc[ni], 0, 0, 0);
                    sacc[ni] = __builtin_amdgcn_mfma_f32_16x16x32_bf16(qfl[kk], hfh, sacc[ni], 0, 0, 0);
                }
            }
        }
        u64 am[4][2];
#pragma unroll
        for (int r = 0; r < 4; r++) {
            am[r][0] = amb[(long)(quad * 4 + r) * (NN / 64) + jc * 2 + 0];
            am[r][1] = amb[(long)(quad * 4 + r) * (NN / 64) + jc * 2 + 1];
        }
#pragma unroll
        for (int ni = 0; ni < 8; ni++) {
#pragma unroll
            for (int r = 0; r < 4; r++) {
                float v = sacc[ni][r] + ay_[r];
                v = v > 0.f ? v : ALPHA_ * v;
                int bit = (int)((am[r][ni >> 2] >> ((ni * 16 + l16) & 63)) & 1);
                float pv = __expf((bit ? v : NEGV) - mrow[r]) * linv[r];
                pw[(quad * 4 + r) * LDP + ni * 16 + l16] = f2bf(pv);
            }
        }
        // wave-private staging; in-wave lgkmcnt ordering suffices (no barrier)
#pragma unroll
        for (int s2 = 0; s2 < 4; s2++) {
            int seg = quad * 4 + s2;
            uint4 v = *(const uint4*)(&pw[l16 * LDP + seg * 8]);
            *(uint4*)(&P[((long)bz * NN + i0 + l16) * NN + jz * JW + jc * 128 + seg * 8]) = v;
        }
    }
}

// ---------------- e = X_bf16[*,512] @ W_f32[5,512]^T (fp32 out) ----------------
__global__ void e_kernel(const bf16* __restrict__ X, const float* __restrict__ Wt,
                         float* __restrict__ out) {
    int lane = threadIdx.x & 63, w = threadIdx.x >> 6;
    long row = (long)blockIdx.x * 4 + w;
    uint4 raw = *(const uint4*)(&X[row * FIN + lane * 8]);
    const bf16* xp = (const bf16*)&raw;
    float xv[8];
    for (int i = 0; i < 8; i++) xv[i] = bf2f(xp[i]);
    for (int e = 0; e < EE; e++) {
        float4 w0 = *(const float4*)(&Wt[e * FIN + lane * 8]);
        float4 w1 = *(const float4*)(&Wt[e * FIN + lane * 8 + 4]);
        float p = xv[0] * w0.x + xv[1] * w0.y + xv[2] * w0.z + xv[3] * w0.w
                + xv[4] * w1.x + xv[5] * w1.y + xv[6] * w1.z + xv[7] * w1.w;
        for (int off = 32; off; off >>= 1) p += __shfl_xor(p, off);
        if (lane == 0) out[row * EE + e] = p;
    }
}

// ---------------- out(fp32) = h1 + h2 + e1.Bw.e2 ----------------
__global__ void final_kernel(float* __restrict__ out,
                             const bf16* __restrict__ h1, const bf16* __restrict__ h2,
                             const float* __restrict__ e1, const float* __restrict__ e2,
                             const float* __restrict__ Bw) {
    long row = blockIdx.x;
    int o = threadIdx.x;
    float a[EE], c[EE];
    for (int i = 0; i < EE; i++) { a[i] = e1[row * EE + i]; c[i] = e2[row * EE + i]; }
    const float* bw = Bw + (long)o * EE * EE;
    float acc = 0.f;
    for (int i = 0; i < EE; i++)
        for (int j = 0; j < EE; j++)
            acc += bw[i * EE + j] * a[i] * c[j];
    long idx = row * FOUT + o;
    out[idx] = acc + bf2f(h1[idx]) + bf2f(h2[idx]);
}

extern "C" void kernel_launch(void* const* d_in, const int* in_sizes, int n_in,
                              void* d_out, int out_size, void* d_ws, size_t ws_size,
                              hipStream_t stream) {
    const float* feat = (const float*)d_in[0];
    const int*   adj  = (const int*)d_in[1];
    const float* W    = (const float*)d_in[2];
    const float* W1   = (const float*)d_in[3];
    const float* W2   = (const float*)d_in[4];
    const float* a1   = (const float*)d_in[5];
    const float* a2   = (const float*)d_in[6];
    const float* a12  = (const float*)d_in[7];
    const float* Lw   = (const float*)d_in[8];
    const float* Rw   = (const float*)d_in[9];
    const float* Bw   = (const float*)d_in[10];
    float* out = (float*)d_out;

    char* ws = (char*)d_ws;
    size_t off = 0;
    auto alloc = [&](size_t bytes) {
        char* p = ws + off;
        off += (bytes + 255) & ~(size_t)255;
        return p;
    };
    bf16* WTh  = (bf16*)alloc((size_t)FOUT * FIN * 2);
    bf16* WTl  = (bf16*)alloc((size_t)FOUT * FIN * 2);
    bf16* W1T  = (bf16*)alloc((size_t)FOUT * FIN * 2);
    bf16* W2T  = (bf16*)alloc((size_t)FOUT * FIN * 2);
    bf16* aTh  = (bf16*)alloc((size_t)FOUT * FOUT * 2);
    bf16* aTl  = (bf16*)alloc((size_t)FOUT * FOUT * 2);
    bf16* fh   = (bf16*)alloc((size_t)BB * NN * FIN * 2);     // 16.8 MB
    bf16* fl   = (bf16*)alloc((size_t)BB * NN * FIN * 2);     // 16.8 MB (fagg later)
    bf16* hh   = (bf16*)alloc((size_t)BB * NN * FOUT * 2);    // 8.4 MB (h1 later)
    bf16* hl   = (bf16*)alloc((size_t)BB * NN * FOUT * 2);    // 8.4 MB (h2 later)
    bf16* featT= (bf16*)alloc((size_t)BB * NN * FIN * 2);     // 16.8 MB
    float* Ay  = (float*)alloc((size_t)BB * NN * 4);
    float2* mlpart = (float2*)alloc((size_t)BB * 4 * NN * 8); // 512 KB
    float2* mlfin  = (float2*)alloc((size_t)BB * NN * 8);     // 128 KB
    float* e1  = (float*)alloc((size_t)BB * NN * EE * 4);
    float* e2  = (float*)alloc((size_t)BB * NN * EE * 4);
    u64* adjm  = (u64*)alloc((size_t)BB * NN * (NN / 64) * 8);// 4.2 MB
    bf16* P    = (bf16*)alloc((size_t)4 * NN * NN * 2);       // 33.5 MB (4 batches)
    // aliases (lifetimes disjoint):  peak ws ~107 MB
    bf16* qh   = (bf16*)d_out;                          // q pair in out (16.8 MB)
    bf16* ql   = qh + (size_t)BB * NN * FOUT;
    bf16* fagg = fl;                                    // fl dead after h-GEMM
    bf16* h1   = hh;                                    // h pair dead after pass2
    bf16* h2   = hl;

    dim3 tb(32, 8, 1);
    // input conversions
    split_f32_bf16<<<(BB * NN * FIN) / (256 * 8), 256, 0, stream>>>(feat, fh, fl);
    pack_adj<<<(BB * NN * NN) / (256 * 4), 256, 0, stream>>>(adj, adjm);
    transpose_split<<<dim3(FOUT / 32, FIN / 32, 1), tb, 0, stream>>>(W, WTh, WTl, FIN, FOUT);
    transpose_split<<<dim3(FOUT / 32, FOUT / 32, 1), tb, 0, stream>>>(a12, aTh, aTl, FOUT, FOUT);
    transpose_f32_bf16<<<dim3(FOUT / 32, FIN / 32, 1), tb, 0, stream>>>(W1, W1T, FIN, FOUT, 0, 0);
    transpose_f32_bf16<<<dim3(FOUT / 32, FIN / 32, 1), tb, 0, stream>>>(W2, W2T, FIN, FOUT, 0, 0);
    transpose_f32_bf16<<<dim3(FIN / 32, NN / 32, BB), tb, 0, stream>>>(
        feat, featT, NN, FIN, (long)NN * FIN, (long)FIN * NN);
    // h = feat @ W   (split precision)
    gemm_bt_split<<<dim3(BB * NN / 128, FOUT / 128, 1), 256, 0, stream>>>(
        fh, fl, WTh, WTl, hh, hl, nullptr, FOUT, FIN);
    // Ay = h @ a2
    ay_kernel<<<BB * NN / 4, 256, 0, stream>>>(hh, hl, a2, Ay);
    // q = h @ a12 + a1   (folds Ax[j] into q.h)
    gemm_bt_split<<<dim3(BB * NN / 128, FOUT / 128, 1), 256, 0, stream>>>(
        hh, hl, aTh, aTl, qh, ql, a1, FOUT, FOUT);
    // pass 1: per-window softmax stats
    pass1_ml<<<dim3(NN / 64, 4, BB), 256, 0, stream>>>(
        qh, ql, hh, hl, adjm, Ay, mlpart);
    ml_merge<<<(BB * NN) / 256, 256, 0, stream>>>(mlpart, mlfin);
    // pass 2 + PV GEMM, in 2 groups of 4 batches (P buffer = 4 batches)
    for (int g = 0; g < 2; g++) {
        pass2_p<<<dim3(NN / 64, 4, 4), 256, 0, stream>>>(
            qh, ql, hh, hl, adjm, Ay, mlfin, P, g * 4);
        gemm_bt<<<dim3(NN / 128, FIN / 128, 4), 256, 0, stream>>>(
            P, featT + (size_t)g * 4 * FIN * NN, fagg + (size_t)g * 4 * NN * FIN,
            FIN, NN, (long)NN * NN, (long)FIN * NN, (long)NN * FIN);
    }
    // h1 = feat @ W1 ; h2 = fagg @ W2
    gemm_bt<<<dim3(BB * NN / 128, FOUT / 128, 1), 256, 0, stream>>>(
        fh, W1T, h1, FOUT, FIN, 0, 0, 0);
    gemm_bt<<<dim3(BB * NN / 128, FOUT / 128, 1), 256, 0, stream>>>(
        fagg, W2T, h2, FOUT, FIN, 0, 0, 0);
    // e1 = feat @ Lw^T ; e2 = fagg @ Rw^T
    e_kernel<<<BB * NN / 4, 256, 0, stream>>>(fh, Lw, e1);
    e_kernel<<<BB * NN / 4, 256, 0, stream>>>(fagg, Rw, e2);
    // out = h1 + h2 + e1.Bw.e2
    final_kernel<<<BB * NN, FOUT, 0, stream>>>(out, h1, h2, e1, e2, Bw);
}

// Round 9
// 614.482 us; speedup vs baseline: 5.7520x; 5.7520x over previous
//
#include <hip/hip_runtime.h>
#include <hip/hip_bf16.h>

#define BB 8
#define NN 2048
#define FIN 512
#define FOUT 256
#define EE 5
#define ALPHA_ 0.2f
#define NEGV -9e15f
#define JW 512   // j-window per jz

typedef __hip_bfloat16 bf16;
typedef __bf16 bf16x8 __attribute__((ext_vector_type(8)));
typedef float f32x4 __attribute__((ext_vector_type(4)));
typedef unsigned long long u64;

__device__ __forceinline__ float bf2f(bf16 x) { return __bfloat162float(x); }
__device__ __forceinline__ bf16 f2bf(float x) { return __float2bfloat16(x); }

// ---------------- split fp32 -> bf16 (hi, lo), flat, 8/thread ----------------
__global__ void split_f32_bf16(const float* __restrict__ in,
                               bf16* __restrict__ hi, bf16* __restrict__ lo) {
    long i = ((long)blockIdx.x * blockDim.x + threadIdx.x) * 8;
    float4 a = *(const float4*)(&in[i]);
    float4 b = *(const float4*)(&in[i + 4]);
    float x[8] = { a.x, a.y, a.z, a.w, b.x, b.y, b.z, b.w };
    bf16 th[8], tl[8];
    for (int k = 0; k < 8; k++) {
        th[k] = f2bf(x[k]);
        tl[k] = f2bf(x[k] - bf2f(th[k]));
    }
    *(uint4*)(&hi[i]) = *(const uint4*)th;
    *(uint4*)(&lo[i]) = *(const uint4*)tl;
}

// ---------------- pack adj (int32 > 0) into 64-col bitmasks ----------------
__global__ void pack_adj(const int* __restrict__ adj, u64* __restrict__ adjm) {
    long wid = (((long)blockIdx.x * 256) + threadIdx.x) >> 6;
    int lane = threadIdx.x & 63;
    long base = wid * 256;
    for (int c = 0; c < 4; c++) {
        int a = adj[base + c * 64 + lane];
        u64 m = __ballot(a > 0);
        if (lane == 0) adjm[base / 64 + c] = m;
    }
}

// ---------------- transpose+split: fp32 [R,C] -> bf16 hi/lo [C,R] ----------------
__global__ void transpose_split(const float* __restrict__ in,
                                bf16* __restrict__ hi, bf16* __restrict__ lo,
                                int R, int C) {
    __shared__ bf16 th[32][33], tl[32][33];
    int c0 = blockIdx.x * 32, r0 = blockIdx.y * 32;
    int x = threadIdx.x, y = threadIdx.y;  // 32 x 8
    for (int k = 0; k < 4; k++) {
        int r = y + k * 8;
        float f = in[(long)(r0 + r) * C + c0 + x];
        bf16 h = f2bf(f);
        th[r][x] = h;
        tl[r][x] = f2bf(f - bf2f(h));
    }
    __syncthreads();
    for (int k = 0; k < 4; k++) {
        int r = y + k * 8;
        hi[(long)(c0 + r) * R + r0 + x] = th[x][r];
        lo[(long)(c0 + r) * R + r0 + x] = tl[x][r];
    }
}

// ---------------- transpose + convert: fp32 [R,C] -> bf16 [C,R] ----------------
__global__ void transpose_f32_bf16(const float* __restrict__ in, bf16* __restrict__ out,
                                   int R, int C, long sin_b, long sout_b) {
    __shared__ bf16 tile[32][33];
    long bi = (long)blockIdx.z * sin_b;
    long bo = (long)blockIdx.z * sout_b;
    int c0 = blockIdx.x * 32, r0 = blockIdx.y * 32;
    int x = threadIdx.x, y = threadIdx.y;
    for (int k = 0; k < 4; k++) {
        int r = y + k * 8;
        tile[r][x] = f2bf(in[bi + (long)(r0 + r) * C + c0 + x]);
    }
    __syncthreads();
    for (int k = 0; k < 4; k++) {
        int r = y + k * 8;
        out[bo + (long)(c0 + r) * R + r0 + x] = tile[x][r];
    }
}

// ---------------- split GEMM: C = (Ah+Al)[M,K] @ (Bh+Bl)[N,K]^T + bias ----------------
__global__ __launch_bounds__(256) void gemm_bt_split(
        const bf16* __restrict__ Ah, const bf16* __restrict__ Al,
        const bf16* __restrict__ Bh, const bf16* __restrict__ Bl,
        bf16* __restrict__ Chi, bf16* __restrict__ Clo,
        const float* __restrict__ bias, int Nn, int K) {
    __shared__ alignas(16) bf16 Ash[128 * 32], Asl[128 * 32];
    __shared__ alignas(16) bf16 Bsh[128 * 32], Bsl[128 * 32];
    int tid = threadIdx.x;
    int lane = tid & 63, ww = tid >> 6;
    int wm = ww >> 1, wn = ww & 1;
    int quad = lane >> 4, l16 = lane & 15;
    int m0 = blockIdx.x * 128, n0 = blockIdx.y * 128;
    f32x4 acc[4][4] = {};
    for (int k0 = 0; k0 < K; k0 += 32) {
        for (int i = 0; i < 2; i++) {
            int idx = tid + i * 256;
            int row = idx >> 2, seg = idx & 3;
            long ao = (long)(m0 + row) * K + k0 + seg * 8;
            long bo = (long)(n0 + row) * K + k0 + seg * 8;
            int so = row * 32 + seg * 8;
            *(uint4*)(&Ash[so]) = *(const uint4*)(&Ah[ao]);
            *(uint4*)(&Asl[so]) = *(const uint4*)(&Al[ao]);
            *(uint4*)(&Bsh[so]) = *(const uint4*)(&Bh[bo]);
            *(uint4*)(&Bsl[so]) = *(const uint4*)(&Bl[bo]);
        }
        __syncthreads();
        bf16x8 afh[4], afl[4], bfh[4], bfl[4];
        for (int mi = 0; mi < 4; mi++) {
            int so = (wm * 64 + mi * 16 + l16) * 32 + quad * 8;
            afh[mi] = *(const bf16x8*)(&Ash[so]);
            afl[mi] = *(const bf16x8*)(&Asl[so]);
        }
        for (int ni = 0; ni < 4; ni++) {
            int so = (wn * 64 + ni * 16 + l16) * 32 + quad * 8;
            bfh[ni] = *(const bf16x8*)(&Bsh[so]);
            bfl[ni] = *(const bf16x8*)(&Bsl[so]);
        }
        for (int mi = 0; mi < 4; mi++)
            for (int ni = 0; ni < 4; ni++) {
                acc[mi][ni] = __builtin_amdgcn_mfma_f32_16x16x32_bf16(afh[mi], bfh[ni], acc[mi][ni], 0, 0, 0);
                acc[mi][ni] = __builtin_amdgcn_mfma_f32_16x16x32_bf16(afh[mi], bfl[ni], acc[mi][ni], 0, 0, 0);
                acc[mi][ni] = __builtin_amdgcn_mfma_f32_16x16x32_bf16(afl[mi], bfh[ni], acc[mi][ni], 0, 0, 0);
            }
        __syncthreads();
    }
    for (int mi = 0; mi < 4; mi++)
        for (int ni = 0; ni < 4; ni++) {
            int col = n0 + wn * 64 + ni * 16 + l16;
            float bv = bias ? bias[col] : 0.f;
            for (int r = 0; r < 4; r++) {
                int row = m0 + wm * 64 + mi * 16 + quad * 4 + r;
                float v = acc[mi][ni][r] + bv;
                bf16 h = f2bf(v);
                Chi[(long)row * Nn + col] = h;
                Clo[(long)row * Nn + col] = f2bf(v - bf2f(h));
            }
        }
}

// ---------------- plain bf16 GEMM: C[M,N] = A[M,K] @ Bt[N,K]^T ----------------
__global__ __launch_bounds__(256) void gemm_bt(
        const bf16* __restrict__ A, const bf16* __restrict__ Bt,
        bf16* __restrict__ C, int Nn, int K, long sA, long sB, long sC) {
    __shared__ alignas(16) bf16 As[128 * 32];
    __shared__ alignas(16) bf16 Bs[128 * 32];
    const bf16* Ab = A + (long)blockIdx.z * sA;
    const bf16* Bb = Bt + (long)blockIdx.z * sB;
    bf16* Cb = C + (long)blockIdx.z * sC;
    int tid = threadIdx.x;
    int lane = tid & 63, ww = tid >> 6;
    int wm = ww >> 1, wn = ww & 1;
    int quad = lane >> 4, l16 = lane & 15;
    int m0 = blockIdx.x * 128, n0 = blockIdx.y * 128;
    f32x4 acc[4][4] = {};
    for (int k0 = 0; k0 < K; k0 += 32) {
        for (int i = 0; i < 2; i++) {
            int idx = tid + i * 256;
            int row = idx >> 2, seg = idx & 3;
            int so = row * 32 + seg * 8;
            *(uint4*)(&As[so]) =
                *(const uint4*)(&Ab[(long)(m0 + row) * K + k0 + seg * 8]);
            *(uint4*)(&Bs[so]) =
                *(const uint4*)(&Bb[(long)(n0 + row) * K + k0 + seg * 8]);
        }
        __syncthreads();
        bf16x8 af[4], bfr[4];
        for (int mi = 0; mi < 4; mi++)
            af[mi] = *(const bf16x8*)(&As[(wm * 64 + mi * 16 + l16) * 32 + quad * 8]);
        for (int ni = 0; ni < 4; ni++)
            bfr[ni] = *(const bf16x8*)(&Bs[(wn * 64 + ni * 16 + l16) * 32 + quad * 8]);
        for (int mi = 0; mi < 4; mi++)
            for (int ni = 0; ni < 4; ni++)
                acc[mi][ni] = __builtin_amdgcn_mfma_f32_16x16x32_bf16(
                    af[mi], bfr[ni], acc[mi][ni], 0, 0, 0);
        __syncthreads();
    }
    for (int mi = 0; mi < 4; mi++)
        for (int ni = 0; ni < 4; ni++) {
            int col = n0 + wn * 64 + ni * 16 + l16;
            for (int r = 0; r < 4; r++) {
                int row = m0 + wm * 64 + mi * 16 + quad * 4 + r;
                Cb[(long)row * Nn + col] = f2bf(acc[mi][ni][r]);
            }
        }
}

// ---------------- Ay[b,n] = (hh+hl)[b,n,:] . a2 ----------------
__global__ void ay_kernel(const bf16* __restrict__ hh, const bf16* __restrict__ hl,
                          const float* __restrict__ a2, float* __restrict__ Ay) {
    int lane = threadIdx.x & 63, w = threadIdx.x >> 6;
    long row = (long)blockIdx.x * 4 + w;
    float p = 0.f;
    for (int i = 0; i < 4; i++) {
        int d = i * 64 + lane;
        p += (bf2f(hh[row * FOUT + d]) + bf2f(hl[row * FOUT + d])) * a2[d];
    }
    for (int off = 32; off; off >>= 1) p += __shfl_xor(p, off);
    if (lane == 0) Ay[row] = p;
}

// ---------------- single score pass: stats + unnormalized P~ ----------------
// EXACT r6 pass1 LDS/staging structure (stride 32, BK=32, i<2 staging) +
// r6 pass2's dedicated pst staging for the P write. #pragma unroll on the kk
// loop keeps qfh[kk]/qfl[kk] constant-indexed (avoids v_movrel waterfalls —
// the r7/r8 failure mode). P~ = exp(s - m_run(jc)); fixup_p normalizes later.
__global__ __launch_bounds__(256) void pass_score(
        const bf16* __restrict__ qh_, const bf16* __restrict__ ql_,
        const bf16* __restrict__ hh_, const bf16* __restrict__ hl_,
        const u64* __restrict__ adjm, const float* __restrict__ Ay,
        float* __restrict__ mpm, float* __restrict__ mpl,
        bf16* __restrict__ P, int b0) {
    __shared__ alignas(16) bf16 Hsh[128 * 32], Hsl[128 * 32];
    __shared__ alignas(16) bf16 pst[4][16 * 128];   // dedicated; never aliases Hs
    int tid = threadIdx.x;
    int lane = tid & 63, w = tid >> 6;
    int quad = lane >> 4, l16 = lane & 15;
    int bz = blockIdx.z, b = b0 + bz, jz = blockIdx.y;
    int i0 = blockIdx.x * 64 + w * 16;
    long qoff = ((long)b * NN + i0) * FOUT;
    const bf16* hbh = hh_ + ((long)b * NN + (long)jz * JW) * FOUT;
    const bf16* hbl = hl_ + ((long)b * NN + (long)jz * JW) * FOUT;
    const u64* amb = adjm + ((long)b * NN + i0) * (NN / 64) + jz * (JW / 64);
    bf16* pw = pst[w];

    bf16x8 qfh[8], qfl[8];
#pragma unroll
    for (int kk = 0; kk < 8; kk++) {
        qfh[kk] = *(const bf16x8*)(&qh_[qoff + (long)l16 * FOUT + kk * 32 + quad * 8]);
        qfl[kk] = *(const bf16x8*)(&ql_[qoff + (long)l16 * FOUT + kk * 32 + quad * 8]);
    }
    float ay_[4];
#pragma unroll
    for (int r = 0; r < 4; r++) ay_[r] = Ay[(long)b * NN + i0 + quad * 4 + r];

    float m_[4], l_[4];
#pragma unroll
    for (int r = 0; r < 4; r++) { m_[r] = -3.0e38f; l_[r] = 0.f; }

    for (int jc = 0; jc < JW / 128; jc++) {
        f32x4 sacc[8] = {};
#pragma unroll
        for (int kk = 0; kk < 8; kk++) {
            __syncthreads();
#pragma unroll
            for (int i = 0; i < 2; i++) {
                int idx = tid + i * 256;
                int row = idx >> 2, seg = idx & 3;
                long go = (long)(jc * 128 + row) * FOUT + kk * 32 + seg * 8;
                int so = row * 32 + seg * 8;
                *(uint4*)(&Hsh[so]) = *(const uint4*)(&hbh[go]);
                *(uint4*)(&Hsl[so]) = *(const uint4*)(&hbl[go]);
            }
            __syncthreads();
#pragma unroll
            for (int ni = 0; ni < 8; ni++) {
                int so = (ni * 16 + l16) * 32 + quad * 8;
                bf16x8 hfh = *(const bf16x8*)(&Hsh[so]);
                bf16x8 hfl = *(const bf16x8*)(&Hsl[so]);
                sacc[ni] = __builtin_amdgcn_mfma_f32_16x16x32_bf16(qfh[kk], hfh, sacc[ni], 0, 0, 0);
                sacc[ni] = __builtin_amdgcn_mfma_f32_16x16x32_bf16(qfh[kk], hfl, sacc[ni], 0, 0, 0);
                sacc[ni] = __builtin_amdgcn_mfma_f32_16x16x32_bf16(qfl[kk], hfh, sacc[ni], 0, 0, 0);
            }
        }
        u64 am[4][2];
#pragma unroll
        for (int r = 0; r < 4; r++) {
            am[r][0] = amb[(long)(quad * 4 + r) * (NN / 64) + jc * 2 + 0];
            am[r][1] = amb[(long)(quad * 4 + r) * (NN / 64) + jc * 2 + 1];
        }
        // in-place leaky relu + mask
#pragma unroll
        for (int ni = 0; ni < 8; ni++)
#pragma unroll
            for (int r = 0; r < 4; r++) {
                float v = sacc[ni][r] + ay_[r];
                v = v > 0.f ? v : ALPHA_ * v;
                int bit = (int)((am[r][ni >> 2] >> ((ni * 16 + l16) & 63)) & 1);
                sacc[ni][r] = bit ? v : NEGV;
            }
        // online m/l; overwrite sacc with exp(s - m_run)
#pragma unroll
        for (int r = 0; r < 4; r++) {
            float mc = -3.0e38f;
#pragma unroll
            for (int ni = 0; ni < 8; ni++) mc = fmaxf(mc, sacc[ni][r]);
            for (int off = 8; off; off >>= 1) mc = fmaxf(mc, __shfl_xor(mc, off));
            float mnew = fmaxf(m_[r], mc);
            float scale = __expf(m_[r] - mnew);
            float ps = 0.f;
#pragma unroll
            for (int ni = 0; ni < 8; ni++) {
                float p = __expf(sacc[ni][r] - mnew);
                sacc[ni][r] = p;
                ps += p;
            }
            for (int off = 8; off; off >>= 1) ps += __shfl_xor(ps, off);
            l_[r] = l_[r] * scale + ps;
            m_[r] = mnew;
            if (l16 == 0)
                mpm[(((long)bz * 4 + jz) * 4 + jc) * NN + i0 + quad * 4 + r] = mnew;
        }
        // P~ chunk -> dedicated wave-private pst -> 16B global stores
#pragma unroll
        for (int ni = 0; ni < 8; ni++)
#pragma unroll
            for (int r = 0; r < 4; r++)
                pw[(quad * 4 + r) * 128 + ni * 16 + l16] = f2bf(sacc[ni][r]);
#pragma unroll
        for (int s2 = 0; s2 < 4; s2++) {
            int seg = quad * 4 + s2;
            uint4 v = *(const uint4*)(&pw[l16 * 128 + seg * 8]);
            *(uint4*)(&P[((long)bz * NN + i0 + l16) * NN + jz * JW + jc * 128 + seg * 8]) = v;
        }
    }
    if (l16 == 0)
#pragma unroll
        for (int r = 0; r < 4; r++)
            mpl[((long)bz * 4 + jz) * NN + i0 + quad * 4 + r] = l_[r];
}

// ---------------- merge window stats -> (m, 1/l) per row (one group) ----------------
__global__ void ml_merge(const float* __restrict__ mpm, const float* __restrict__ mpl,
                         float2* __restrict__ mlfin) {
    long row = (long)blockIdx.x * blockDim.x + threadIdx.x;  // [0, 4*NN)
    long bz = row / NN, n = row % NN;
    float mw[4];
    float m = -3.0e38f;
    for (int jz = 0; jz < 4; jz++) {
        mw[jz] = mpm[((bz * 4 + jz) * 4 + 3) * NN + n];
        m = fmaxf(m, mw[jz]);
    }
    float l = 0.f;
    for (int jz = 0; jz < 4; jz++)
        l += mpl[(bz * 4 + jz) * NN + n] * __expf(mw[jz] - m);
    mlfin[row] = make_float2(m, 1.f / l);
}

// ---------------- fixup: P *= exp(m_chunk - m_glob) / l ----------------
__global__ __launch_bounds__(256) void fixup_p(
        bf16* __restrict__ P, const float* __restrict__ mpm,
        const float2* __restrict__ mlfin) {
    int row = blockIdx.x, bz = blockIdx.y;
    int t = threadIdx.x;
    int jz = t >> 6, jc = (t >> 4) & 3;
    float2 mf = mlfin[(long)bz * NN + row];
    float scale = __expf(mpm[(((long)bz * 4 + jz) * 4 + jc) * NN + row] - mf.x) * mf.y;
    long base = ((long)bz * NN + row) * NN + t * 8;
    uint4 v = *(const uint4*)(&P[base]);
    bf16* pv = (bf16*)&v;
    bf16 o[8];
    for (int k = 0; k < 8; k++) o[k] = f2bf(bf2f(pv[k]) * scale);
    *(uint4*)(&P[base]) = *(const uint4*)o;
}

// ---------------- e = X_bf16[*,512] @ W_f32[5,512]^T (fp32 out) ----------------
__global__ void e_kernel(const bf16* __restrict__ X, const float* __restrict__ Wt,
                         float* __restrict__ out) {
    int lane = threadIdx.x & 63, w = threadIdx.x >> 6;
    long row = (long)blockIdx.x * 4 + w;
    uint4 raw = *(const uint4*)(&X[row * FIN + lane * 8]);
    const bf16* xp = (const bf16*)&raw;
    float xv[8];
    for (int i = 0; i < 8; i++) xv[i] = bf2f(xp[i]);
    for (int e = 0; e < EE; e++) {
        float4 w0 = *(const float4*)(&Wt[e * FIN + lane * 8]);
        float4 w1 = *(const float4*)(&Wt[e * FIN + lane * 8 + 4]);
        float p = xv[0] * w0.x + xv[1] * w0.y + xv[2] * w0.z + xv[3] * w0.w
                + xv[4] * w1.x + xv[5] * w1.y + xv[6] * w1.z + xv[7] * w1.w;
        for (int off = 32; off; off >>= 1) p += __shfl_xor(p, off);
        if (lane == 0) out[row * EE + e] = p;
    }
}

// ---------------- out(fp32) = h1 + h2 + e1.Bw.e2 ----------------
__global__ void final_kernel(float* __restrict__ out,
                             const bf16* __restrict__ h1, const bf16* __restrict__ h2,
                             const float* __restrict__ e1, const float* __restrict__ e2,
                             const float* __restrict__ Bw) {
    long row = blockIdx.x;
    int o = threadIdx.x;
    float a[EE], c[EE];
    for (int i = 0; i < EE; i++) { a[i] = e1[row * EE + i]; c[i] = e2[row * EE + i]; }
    const float* bw = Bw + (long)o * EE * EE;
    float acc = 0.f;
    for (int i = 0; i < EE; i++)
        for (int j = 0; j < EE; j++)
            acc += bw[i * EE + j] * a[i] * c[j];
    long idx = row * FOUT + o;
    out[idx] = acc + bf2f(h1[idx]) + bf2f(h2[idx]);
}

extern "C" void kernel_launch(void* const* d_in, const int* in_sizes, int n_in,
                              void* d_out, int out_size, void* d_ws, size_t ws_size,
                              hipStream_t stream) {
    const float* feat = (const float*)d_in[0];
    const int*   adj  = (const int*)d_in[1];
    const float* W    = (const float*)d_in[2];
    const float* W1   = (const float*)d_in[3];
    const float* W2   = (const float*)d_in[4];
    const float* a1   = (const float*)d_in[5];
    const float* a2   = (const float*)d_in[6];
    const float* a12  = (const float*)d_in[7];
    const float* Lw   = (const float*)d_in[8];
    const float* Rw   = (const float*)d_in[9];
    const float* Bw   = (const float*)d_in[10];
    float* out = (float*)d_out;

    char* ws = (char*)d_ws;
    size_t off = 0;
    auto alloc = [&](size_t bytes) {
        char* p = ws + off;
        off += (bytes + 255) & ~(size_t)255;
        return p;
    };
    bf16* WTh  = (bf16*)alloc((size_t)FOUT * FIN * 2);
    bf16* WTl  = (bf16*)alloc((size_t)FOUT * FIN * 2);
    bf16* W1T  = (bf16*)alloc((size_t)FOUT * FIN * 2);
    bf16* W2T  = (bf16*)alloc((size_t)FOUT * FIN * 2);
    bf16* aTh  = (bf16*)alloc((size_t)FOUT * FOUT * 2);
    bf16* aTl  = (bf16*)alloc((size_t)FOUT * FOUT * 2);
    bf16* fh   = (bf16*)alloc((size_t)BB * NN * FIN * 2);     // 16.8 MB
    bf16* fl   = (bf16*)alloc((size_t)BB * NN * FIN * 2);     // 16.8 MB (fagg later)
    bf16* hh   = (bf16*)alloc((size_t)BB * NN * FOUT * 2);    // 8.4 MB (h1 later)
    bf16* hl   = (bf16*)alloc((size_t)BB * NN * FOUT * 2);    // 8.4 MB (h2 later)
    bf16* featT= (bf16*)alloc((size_t)BB * NN * FIN * 2);     // 16.8 MB
    float* Ay  = (float*)alloc((size_t)BB * NN * 4);
    float* mpm = (float*)alloc((size_t)4 * 4 * 4 * NN * 4);   // 512 KB (per group)
    float* mpl = (float*)alloc((size_t)4 * 4 * NN * 4);       // 128 KB
    float2* mlfin = (float2*)alloc((size_t)4 * NN * 8);       // 64 KB
    float* e1  = (float*)alloc((size_t)BB * NN * EE * 4);
    float* e2  = (float*)alloc((size_t)BB * NN * EE * 4);
    u64* adjm  = (u64*)alloc((size_t)BB * NN * (NN / 64) * 8);// 4.2 MB
    bf16* P    = (bf16*)alloc((size_t)4 * NN * NN * 2);       // 33.5 MB (4 batches)
    // aliases (lifetimes disjoint):  peak ws ~107 MB
    bf16* qh   = (bf16*)d_out;                          // q pair in out (16.8 MB)
    bf16* ql   = qh + (size_t)BB * NN * FOUT;
    bf16* fagg = fl;                                    // fl dead after h-GEMM
    bf16* h1   = hh;                                    // h pair dead after scores
    bf16* h2   = hl;

    dim3 tb(32, 8, 1);
    // input conversions
    split_f32_bf16<<<(BB * NN * FIN) / (256 * 8), 256, 0, stream>>>(feat, fh, fl);
    pack_adj<<<(BB * NN * NN) / (256 * 4), 256, 0, stream>>>(adj, adjm);
    transpose_split<<<dim3(FOUT / 32, FIN / 32, 1), tb, 0, stream>>>(W, WTh, WTl, FIN, FOUT);
    transpose_split<<<dim3(FOUT / 32, FOUT / 32, 1), tb, 0, stream>>>(a12, aTh, aTl, FOUT, FOUT);
    transpose_f32_bf16<<<dim3(FOUT / 32, FIN / 32, 1), tb, 0, stream>>>(W1, W1T, FIN, FOUT, 0, 0);
    transpose_f32_bf16<<<dim3(FOUT / 32, FIN / 32, 1), tb, 0, stream>>>(W2, W2T, FIN, FOUT, 0, 0);
    transpose_f32_bf16<<<dim3(FIN / 32, NN / 32, BB), tb, 0, stream>>>(
        feat, featT, NN, FIN, (long)NN * FIN, (long)FIN * NN);
    // h = feat @ W   (split precision)
    gemm_bt_split<<<dim3(BB * NN / 128, FOUT / 128, 1), 256, 0, stream>>>(
        fh, fl, WTh, WTl, hh, hl, nullptr, FOUT, FIN);
    // Ay = h @ a2
    ay_kernel<<<BB * NN / 4, 256, 0, stream>>>(hh, hl, a2, Ay);
    // q = h @ a12 + a1   (folds Ax[j] into q.h)
    gemm_bt_split<<<dim3(BB * NN / 128, FOUT / 128, 1), 256, 0, stream>>>(
        hh, hl, aTh, aTl, qh, ql, a1, FOUT, FOUT);
    // attention per group of 4 batches: scores+P~ -> merge -> fixup -> PV
    for (int g = 0; g < 2; g++) {
        pass_score<<<dim3(NN / 64, 4, 4), 256, 0, stream>>>(
            qh, ql, hh, hl, adjm, Ay, mpm, mpl, P, g * 4);
        ml_merge<<<(4 * NN) / 256, 256, 0, stream>>>(mpm, mpl, mlfin);
        fixup_p<<<dim3(NN, 4, 1), 256, 0, stream>>>(P, mpm, mlfin);
        gemm_bt<<<dim3(NN / 128, FIN / 128, 4), 256, 0, stream>>>(
            P, featT + (size_t)g * 4 * FIN * NN, fagg + (size_t)g * 4 * NN * FIN,
            FIN, NN, (long)NN * NN, (long)FIN * NN, (long)NN * FIN);
    }
    // h1 = feat @ W1 ; h2 = fagg @ W2
    gemm_bt<<<dim3(BB * NN / 128, FOUT / 128, 1), 256, 0, stream>>>(
        fh, W1T, h1, FOUT, FIN, 0, 0, 0);
    gemm_bt<<<dim3(BB * NN / 128, FOUT / 128, 1), 256, 0, stream>>>(
        fagg, W2T, h2, FOUT, FIN, 0, 0, 0);
    // e1 = feat @ Lw^T ; e2 = fagg @ Rw^T
    e_kernel<<<BB * NN / 4, 256, 0, stream>>>(fh, Lw, e1);
    e_kernel<<<BB * NN / 4, 256, 0, stream>>>(fagg, Rw, e2);
    // out = h1 + h2 + e1.Bw.e2
    final_kernel<<<BB * NN, FOUT, 0, stream>>>(out, h1, h2, e1, e2, Bw);
}

// Round 10
// 552.714 us; speedup vs baseline: 6.3948x; 1.1118x over previous
//
#include <hip/hip_runtime.h>
#include <hip/hip_bf16.h>

#define BB 8
#define NN 2048
#define FIN 512
#define FOUT 256
#define EE 5
#define ALPHA_ 0.2f
#define NEGV -9e15f
#define JW 512   // j-window per jz

typedef __hip_bfloat16 bf16;
typedef __bf16 bf16x8 __attribute__((ext_vector_type(8)));
typedef float f32x4 __attribute__((ext_vector_type(4)));
typedef unsigned long long u64;

__device__ __forceinline__ float bf2f(bf16 x) { return __bfloat162float(x); }
__device__ __forceinline__ bf16 f2bf(float x) { return __float2bfloat16(x); }

// async global->LDS, 16B per lane. LDS dest must be wave-uniform base + lane*16
// (true for all call sites: lds offset == idx*16B with idx = tid + i*256).
__device__ __forceinline__ void async16(const bf16* g, bf16* l) {
    __builtin_amdgcn_global_load_lds(
        (const __attribute__((address_space(1))) void*)g,
        (__attribute__((address_space(3))) void*)l, 16, 0, 0);
}

// ---------------- split fp32 -> bf16 (hi, lo), flat, 8/thread ----------------
__global__ void split_f32_bf16(const float* __restrict__ in,
                               bf16* __restrict__ hi, bf16* __restrict__ lo) {
    long i = ((long)blockIdx.x * blockDim.x + threadIdx.x) * 8;
    float4 a = *(const float4*)(&in[i]);
    float4 b = *(const float4*)(&in[i + 4]);
    float x[8] = { a.x, a.y, a.z, a.w, b.x, b.y, b.z, b.w };
    bf16 th[8], tl[8];
    for (int k = 0; k < 8; k++) {
        th[k] = f2bf(x[k]);
        tl[k] = f2bf(x[k] - bf2f(th[k]));
    }
    *(uint4*)(&hi[i]) = *(const uint4*)th;
    *(uint4*)(&lo[i]) = *(const uint4*)tl;
}

// ---------------- pack adj (int32 > 0) into 64-col bitmasks ----------------
__global__ void pack_adj(const int* __restrict__ adj, u64* __restrict__ adjm) {
    long wid = (((long)blockIdx.x * 256) + threadIdx.x) >> 6;
    int lane = threadIdx.x & 63;
    long base = wid * 256;
    for (int c = 0; c < 4; c++) {
        int a = adj[base + c * 64 + lane];
        u64 m = __ballot(a > 0);
        if (lane == 0) adjm[base / 64 + c] = m;
    }
}

// ---------------- transpose+split: fp32 [R,C] -> bf16 hi/lo [C,R] ----------------
__global__ void transpose_split(const float* __restrict__ in,
                                bf16* __restrict__ hi, bf16* __restrict__ lo,
                                int R, int C) {
    __shared__ bf16 th[32][33], tl[32][33];
    int c0 = blockIdx.x * 32, r0 = blockIdx.y * 32;
    int x = threadIdx.x, y = threadIdx.y;  // 32 x 8
    for (int k = 0; k < 4; k++) {
        int r = y + k * 8;
        float f = in[(long)(r0 + r) * C + c0 + x];
        bf16 h = f2bf(f);
        th[r][x] = h;
        tl[r][x] = f2bf(f - bf2f(h));
    }
    __syncthreads();
    for (int k = 0; k < 4; k++) {
        int r = y + k * 8;
        hi[(long)(c0 + r) * R + r0 + x] = th[x][r];
        lo[(long)(c0 + r) * R + r0 + x] = tl[x][r];
    }
}

// ---------------- transpose + convert: fp32 [R,C] -> bf16 [C,R] ----------------
__global__ void transpose_f32_bf16(const float* __restrict__ in, bf16* __restrict__ out,
                                   int R, int C, long sin_b, long sout_b) {
    __shared__ bf16 tile[32][33];
    long bi = (long)blockIdx.z * sin_b;
    long bo = (long)blockIdx.z * sout_b;
    int c0 = blockIdx.x * 32, r0 = blockIdx.y * 32;
    int x = threadIdx.x, y = threadIdx.y;
    for (int k = 0; k < 4; k++) {
        int r = y + k * 8;
        tile[r][x] = f2bf(in[bi + (long)(r0 + r) * C + c0 + x]);
    }
    __syncthreads();
    for (int k = 0; k < 4; k++) {
        int r = y + k * 8;
        out[bo + (long)(c0 + r) * R + r0 + x] = tile[x][r];
    }
}

// ---------------- split GEMM: C = (Ah+Al)[M,K] @ (Bh+Bl)[N,K]^T + bias ----------------
__global__ __launch_bounds__(256) void gemm_bt_split(
        const bf16* __restrict__ Ah, const bf16* __restrict__ Al,
        const bf16* __restrict__ Bh, const bf16* __restrict__ Bl,
        bf16* __restrict__ Chi, bf16* __restrict__ Clo,
        const float* __restrict__ bias, int Nn, int K) {
    __shared__ alignas(16) bf16 Ash[128 * 32], Asl[128 * 32];
    __shared__ alignas(16) bf16 Bsh[128 * 32], Bsl[128 * 32];
    int tid = threadIdx.x;
    int lane = tid & 63, ww = tid >> 6;
    int wm = ww >> 1, wn = ww & 1;
    int quad = lane >> 4, l16 = lane & 15;
    int m0 = blockIdx.x * 128, n0 = blockIdx.y * 128;
    f32x4 acc[4][4] = {};
    for (int k0 = 0; k0 < K; k0 += 32) {
#pragma unroll
        for (int i = 0; i < 2; i++) {
            int idx = tid + i * 256;
            int row = idx >> 2, seg = idx & 3;
            long ao = (long)(m0 + row) * K + k0 + seg * 8;
            long bo = (long)(n0 + row) * K + k0 + seg * 8;
            async16(&Ah[ao], &Ash[idx * 8]);
            async16(&Al[ao], &Asl[idx * 8]);
            async16(&Bh[bo], &Bsh[idx * 8]);
            async16(&Bl[bo], &Bsl[idx * 8]);
        }
        __syncthreads();
        bf16x8 afh[4], afl[4], bfh[4], bfl[4];
        for (int mi = 0; mi < 4; mi++) {
            int so = (wm * 64 + mi * 16 + l16) * 32 + quad * 8;
            afh[mi] = *(const bf16x8*)(&Ash[so]);
            afl[mi] = *(const bf16x8*)(&Asl[so]);
        }
        for (int ni = 0; ni < 4; ni++) {
            int so = (wn * 64 + ni * 16 + l16) * 32 + quad * 8;
            bfh[ni] = *(const bf16x8*)(&Bsh[so]);
            bfl[ni] = *(const bf16x8*)(&Bsl[so]);
        }
        for (int mi = 0; mi < 4; mi++)
            for (int ni = 0; ni < 4; ni++) {
                acc[mi][ni] = __builtin_amdgcn_mfma_f32_16x16x32_bf16(afh[mi], bfh[ni], acc[mi][ni], 0, 0, 0);
                acc[mi][ni] = __builtin_amdgcn_mfma_f32_16x16x32_bf16(afh[mi], bfl[ni], acc[mi][ni], 0, 0, 0);
                acc[mi][ni] = __builtin_amdgcn_mfma_f32_16x16x32_bf16(afl[mi], bfh[ni], acc[mi][ni], 0, 0, 0);
            }
        __syncthreads();
    }
    for (int mi = 0; mi < 4; mi++)
        for (int ni = 0; ni < 4; ni++) {
            int col = n0 + wn * 64 + ni * 16 + l16;
            float bv = bias ? bias[col] : 0.f;
            for (int r = 0; r < 4; r++) {
                int row = m0 + wm * 64 + mi * 16 + quad * 4 + r;
                float v = acc[mi][ni][r] + bv;
                bf16 h = f2bf(v);
                Chi[(long)row * Nn + col] = h;
                Clo[(long)row * Nn + col] = f2bf(v - bf2f(h));
            }
        }
}

// ---------------- plain bf16 GEMM: C[M,N] = A[M,K] @ Bt[N,K]^T ----------------
__global__ __launch_bounds__(256) void gemm_bt(
        const bf16* __restrict__ A, const bf16* __restrict__ Bt,
        bf16* __restrict__ C, int Nn, int K, long sA, long sB, long sC) {
    __shared__ alignas(16) bf16 As[128 * 32];
    __shared__ alignas(16) bf16 Bs[128 * 32];
    const bf16* Ab = A + (long)blockIdx.z * sA;
    const bf16* Bb = Bt + (long)blockIdx.z * sB;
    bf16* Cb = C + (long)blockIdx.z * sC;
    int tid = threadIdx.x;
    int lane = tid & 63, ww = tid >> 6;
    int wm = ww >> 1, wn = ww & 1;
    int quad = lane >> 4, l16 = lane & 15;
    int m0 = blockIdx.x * 128, n0 = blockIdx.y * 128;
    f32x4 acc[4][4] = {};
    for (int k0 = 0; k0 < K; k0 += 32) {
#pragma unroll
        for (int i = 0; i < 2; i++) {
            int idx = tid + i * 256;
            int row = idx >> 2, seg = idx & 3;
            async16(&Ab[(long)(m0 + row) * K + k0 + seg * 8], &As[idx * 8]);
            async16(&Bb[(long)(n0 + row) * K + k0 + seg * 8], &Bs[idx * 8]);
        }
        __syncthreads();
        bf16x8 af[4], bfr[4];
        for (int mi = 0; mi < 4; mi++)
            af[mi] = *(const bf16x8*)(&As[(wm * 64 + mi * 16 + l16) * 32 + quad * 8]);
        for (int ni = 0; ni < 4; ni++)
            bfr[ni] = *(const bf16x8*)(&Bs[(wn * 64 + ni * 16 + l16) * 32 + quad * 8]);
        for (int mi = 0; mi < 4; mi++)
            for (int ni = 0; ni < 4; ni++)
                acc[mi][ni] = __builtin_amdgcn_mfma_f32_16x16x32_bf16(
                    af[mi], bfr[ni], acc[mi][ni], 0, 0, 0);
        __syncthreads();
    }
    for (int mi = 0; mi < 4; mi++)
        for (int ni = 0; ni < 4; ni++) {
            int col = n0 + wn * 64 + ni * 16 + l16;
            for (int r = 0; r < 4; r++) {
                int row = m0 + wm * 64 + mi * 16 + quad * 4 + r;
                Cb[(long)row * Nn + col] = f2bf(acc[mi][ni][r]);
            }
        }
}

// ---------------- Ay[b,n] = (hh+hl)[b,n,:] . a2 ----------------
__global__ void ay_kernel(const bf16* __restrict__ hh, const bf16* __restrict__ hl,
                          const float* __restrict__ a2, float* __restrict__ Ay) {
    int lane = threadIdx.x & 63, w = threadIdx.x >> 6;
    long row = (long)blockIdx.x * 4 + w;
    float p = 0.f;
    for (int i = 0; i < 4; i++) {
        int d = i * 64 + lane;
        p += (bf2f(hh[row * FOUT + d]) + bf2f(hl[row * FOUT + d])) * a2[d];
    }
    for (int off = 32; off; off >>= 1) p += __shfl_xor(p, off);
    if (lane == 0) Ay[row] = p;
}

// ---------------- single score pass: stats + unnormalized P~ (all 8 batches) ----------------
__global__ __launch_bounds__(256) void pass_score(
        const bf16* __restrict__ qh_, const bf16* __restrict__ ql_,
        const bf16* __restrict__ hh_, const bf16* __restrict__ hl_,
        const u64* __restrict__ adjm, const float* __restrict__ Ay,
        float* __restrict__ mpm, float* __restrict__ mpl,
        bf16* __restrict__ P) {
    __shared__ alignas(16) bf16 Hsh[128 * 32], Hsl[128 * 32];
    __shared__ alignas(16) bf16 pst[4][16 * 128];   // dedicated; never aliases Hs
    int tid = threadIdx.x;
    int lane = tid & 63, w = tid >> 6;
    int quad = lane >> 4, l16 = lane & 15;
    int b = blockIdx.z, jz = blockIdx.y;
    int i0 = blockIdx.x * 64 + w * 16;
    long qoff = ((long)b * NN + i0) * FOUT;
    const bf16* hbh = hh_ + ((long)b * NN + (long)jz * JW) * FOUT;
    const bf16* hbl = hl_ + ((long)b * NN + (long)jz * JW) * FOUT;
    const u64* amb = adjm + ((long)b * NN + i0) * (NN / 64) + jz * (JW / 64);
    bf16* pw = pst[w];

    bf16x8 qfh[8], qfl[8];
#pragma unroll
    for (int kk = 0; kk < 8; kk++) {
        qfh[kk] = *(const bf16x8*)(&qh_[qoff + (long)l16 * FOUT + kk * 32 + quad * 8]);
        qfl[kk] = *(const bf16x8*)(&ql_[qoff + (long)l16 * FOUT + kk * 32 + quad * 8]);
    }
    float ay_[4];
#pragma unroll
    for (int r = 0; r < 4; r++) ay_[r] = Ay[(long)b * NN + i0 + quad * 4 + r];

    float m_[4], l_[4];
#pragma unroll
    for (int r = 0; r < 4; r++) { m_[r] = -3.0e38f; l_[r] = 0.f; }

    for (int jc = 0; jc < JW / 128; jc++) {
        f32x4 sacc[8] = {};
#pragma unroll
        for (int kk = 0; kk < 8; kk++) {
            __syncthreads();
#pragma unroll
            for (int i = 0; i < 2; i++) {
                int idx = tid + i * 256;
                int row = idx >> 2, seg = idx & 3;
                long go = (long)(jc * 128 + row) * FOUT + kk * 32 + seg * 8;
                async16(&hbh[go], &Hsh[idx * 8]);
                async16(&hbl[go], &Hsl[idx * 8]);
            }
            __syncthreads();
#pragma unroll
            for (int ni = 0; ni < 8; ni++) {
                int so = (ni * 16 + l16) * 32 + quad * 8;
                bf16x8 hfh = *(const bf16x8*)(&Hsh[so]);
                bf16x8 hfl = *(const bf16x8*)(&Hsl[so]);
                sacc[ni] = __builtin_amdgcn_mfma_f32_16x16x32_bf16(qfh[kk], hfh, sacc[ni], 0, 0, 0);
                sacc[ni] = __builtin_amdgcn_mfma_f32_16x16x32_bf16(qfh[kk], hfl, sacc[ni], 0, 0, 0);
                sacc[ni] = __builtin_amdgcn_mfma_f32_16x16x32_bf16(qfl[kk], hfh, sacc[ni], 0, 0, 0);
            }
        }
        u64 am[4][2];
#pragma unroll
        for (int r = 0; r < 4; r++) {
            am[r][0] = amb[(long)(quad * 4 + r) * (NN / 64) + jc * 2 + 0];
            am[r][1] = amb[(long)(quad * 4 + r) * (NN / 64) + jc * 2 + 1];
        }
#pragma unroll
        for (int ni = 0; ni < 8; ni++)
#pragma unroll
            for (int r = 0; r < 4; r++) {
                float v = sacc[ni][r] + ay_[r];
                v = v > 0.f ? v : ALPHA_ * v;
                int bit = (int)((am[r][ni >> 2] >> ((ni * 16 + l16) & 63)) & 1);
                sacc[ni][r] = bit ? v : NEGV;
            }
#pragma unroll
        for (int r = 0; r < 4; r++) {
            float mc = -3.0e38f;
#pragma unroll
            for (int ni = 0; ni < 8; ni++) mc = fmaxf(mc, sacc[ni][r]);
            for (int off = 8; off; off >>= 1) mc = fmaxf(mc, __shfl_xor(mc, off));
            float mnew = fmaxf(m_[r], mc);
            float scale = __expf(m_[r] - mnew);
            float ps = 0.f;
#pragma unroll
            for (int ni = 0; ni < 8; ni++) {
                float p = __expf(sacc[ni][r] - mnew);
                sacc[ni][r] = p;
                ps += p;
            }
            for (int off = 8; off; off >>= 1) ps += __shfl_xor(ps, off);
            l_[r] = l_[r] * scale + ps;
            m_[r] = mnew;
            if (l16 == 0)
                mpm[(((long)b * 4 + jz) * 4 + jc) * NN + i0 + quad * 4 + r] = mnew;
        }
#pragma unroll
        for (int ni = 0; ni < 8; ni++)
#pragma unroll
            for (int r = 0; r < 4; r++)
                pw[(quad * 4 + r) * 128 + ni * 16 + l16] = f2bf(sacc[ni][r]);
#pragma unroll
        for (int s2 = 0; s2 < 4; s2++) {
            int seg = quad * 4 + s2;
            uint4 v = *(const uint4*)(&pw[l16 * 128 + seg * 8]);
            *(uint4*)(&P[((long)b * NN + i0 + l16) * NN + jz * JW + jc * 128 + seg * 8]) = v;
        }
    }
    if (l16 == 0)
#pragma unroll
        for (int r = 0; r < 4; r++)
            mpl[((long)b * 4 + jz) * NN + i0 + quad * 4 + r] = l_[r];
}

// ---------------- merge window stats -> (m, 1/l) per row (all batches) ----------------
__global__ void ml_merge(const float* __restrict__ mpm, const float* __restrict__ mpl,
                         float2* __restrict__ mlfin) {
    long row = (long)blockIdx.x * blockDim.x + threadIdx.x;  // [0, BB*NN)
    long b = row / NN, n = row % NN;
    float mw[4];
    float m = -3.0e38f;
    for (int jz = 0; jz < 4; jz++) {
        mw[jz] = mpm[((b * 4 + jz) * 4 + 3) * NN + n];
        m = fmaxf(m, mw[jz]);
    }
    float l = 0.f;
    for (int jz = 0; jz < 4; jz++)
        l += mpl[(b * 4 + jz) * NN + n] * __expf(mw[jz] - m);
    mlfin[row] = make_float2(m, 1.f / l);
}

// ---------------- fixup: P *= exp(m_chunk - m_glob) / l ----------------
__global__ __launch_bounds__(256) void fixup_p(
        bf16* __restrict__ P, const float* __restrict__ mpm,
        const float2* __restrict__ mlfin) {
    int row = blockIdx.x, b = blockIdx.y;
    int t = threadIdx.x;
    int jz = t >> 6, jc = (t >> 4) & 3;
    float2 mf = mlfin[(long)b * NN + row];
    float scale = __expf(mpm[(((long)b * 4 + jz) * 4 + jc) * NN + row] - mf.x) * mf.y;
    long base = ((long)b * NN + row) * NN + t * 8;
    uint4 v = *(const uint4*)(&P[base]);
    bf16* pv = (bf16*)&v;
    bf16 o[8];
    for (int k = 0; k < 8; k++) o[k] = f2bf(bf2f(pv[k]) * scale);
    *(uint4*)(&P[base]) = *(const uint4*)o;
}

// ---------------- e = X_bf16[*,512] @ W_f32[5,512]^T (fp32 out) ----------------
__global__ void e_kernel(const bf16* __restrict__ X, const float* __restrict__ Wt,
                         float* __restrict__ out) {
    int lane = threadIdx.x & 63, w = threadIdx.x >> 6;
    long row = (long)blockIdx.x * 4 + w;
    uint4 raw = *(const uint4*)(&X[row * FIN + lane * 8]);
    const bf16* xp = (const bf16*)&raw;
    float xv[8];
    for (int i = 0; i < 8; i++) xv[i] = bf2f(xp[i]);
    for (int e = 0; e < EE; e++) {
        float4 w0 = *(const float4*)(&Wt[e * FIN + lane * 8]);
        float4 w1 = *(const float4*)(&Wt[e * FIN + lane * 8 + 4]);
        float p = xv[0] * w0.x + xv[1] * w0.y + xv[2] * w0.z + xv[3] * w0.w
                + xv[4] * w1.x + xv[5] * w1.y + xv[6] * w1.z + xv[7] * w1.w;
        for (int off = 32; off; off >>= 1) p += __shfl_xor(p, off);
        if (lane == 0) out[row * EE + e] = p;
    }
}

// ---------------- out(fp32) = h1 + h2 + e1.Bw.e2 ----------------
__global__ void final_kernel(float* __restrict__ out,
                             const bf16* __restrict__ h1, const bf16* __restrict__ h2,
                             const float* __restrict__ e1, const float* __restrict__ e2,
                             const float* __restrict__ Bw) {
    long row = blockIdx.x;
    int o = threadIdx.x;
    float a[EE], c[EE];
    for (int i = 0; i < EE; i++) { a[i] = e1[row * EE + i]; c[i] = e2[row * EE + i]; }
    const float* bw = Bw + (long)o * EE * EE;
    float acc = 0.f;
    for (int i = 0; i < EE; i++)
        for (int j = 0; j < EE; j++)
            acc += bw[i * EE + j] * a[i] * c[j];
    long idx = row * FOUT + o;
    out[idx] = acc + bf2f(h1[idx]) + bf2f(h2[idx]);
}

extern "C" void kernel_launch(void* const* d_in, const int* in_sizes, int n_in,
                              void* d_out, int out_size, void* d_ws, size_t ws_size,
                              hipStream_t stream) {
    const float* feat = (const float*)d_in[0];
    const int*   adj  = (const int*)d_in[1];
    const float* W    = (const float*)d_in[2];
    const float* W1   = (const float*)d_in[3];
    const float* W2   = (const float*)d_in[4];
    const float* a1   = (const float*)d_in[5];
    const float* a2   = (const float*)d_in[6];
    const float* a12  = (const float*)d_in[7];
    const float* Lw   = (const float*)d_in[8];
    const float* Rw   = (const float*)d_in[9];
    const float* Bw   = (const float*)d_in[10];
    float* out = (float*)d_out;

    char* ws = (char*)d_ws;
    size_t off = 0;
    auto alloc = [&](size_t bytes) {
        char* p = ws + off;
        off += (bytes + 255) & ~(size_t)255;
        return p;
    };
    bf16* WTh  = (bf16*)alloc((size_t)FOUT * FIN * 2);
    bf16* WTl  = (bf16*)alloc((size_t)FOUT * FIN * 2);
    bf16* W1T  = (bf16*)alloc((size_t)FOUT * FIN * 2);
    bf16* W2T  = (bf16*)alloc((size_t)FOUT * FIN * 2);
    bf16* aTh  = (bf16*)alloc((size_t)FOUT * FOUT * 2);
    bf16* aTl  = (bf16*)alloc((size_t)FOUT * FOUT * 2);
    bf16* fh   = (bf16*)alloc((size_t)BB * NN * FIN * 2);     // 16.8 MB
    bf16* fl   = (bf16*)alloc((size_t)BB * NN * FIN * 2);     // 16.8 MB (fagg later)
    bf16* hh   = (bf16*)alloc((size_t)BB * NN * FOUT * 2);    // 8.4 MB (h1 later)
    bf16* hl   = (bf16*)alloc((size_t)BB * NN * FOUT * 2);    // 8.4 MB (h2 later)
    bf16* featT= (bf16*)alloc((size_t)BB * NN * FIN * 2);     // 16.8 MB
    float* Ay  = (float*)alloc((size_t)BB * NN * 4);
    float* mpm = (float*)alloc((size_t)BB * 4 * 4 * NN * 4);  // 1 MB
    float* mpl = (float*)alloc((size_t)BB * 4 * NN * 4);      // 256 KB
    float2* mlfin = (float2*)alloc((size_t)BB * NN * 8);      // 128 KB
    float* e1  = (float*)alloc((size_t)BB * NN * EE * 4);
    float* e2  = (float*)alloc((size_t)BB * NN * EE * 4);
    u64* adjm  = (u64*)alloc((size_t)BB * NN * (NN / 64) * 8);// 4.2 MB
    bf16* P    = (bf16*)alloc((size_t)BB * NN * NN * 2);      // 67.1 MB (all batches)
    // aliases (lifetimes disjoint):  peak ws ~140 MB (ws is ~512 MB)
    bf16* qh   = (bf16*)d_out;                          // q pair in out (16.8 MB)
    bf16* ql   = qh + (size_t)BB * NN * FOUT;
    bf16* fagg = fl;                                    // fl dead after h-GEMM
    bf16* h1   = hh;                                    // h pair dead after scores
    bf16* h2   = hl;

    dim3 tb(32, 8, 1);
    // input conversions
    split_f32_bf16<<<(BB * NN * FIN) / (256 * 8), 256, 0, stream>>>(feat, fh, fl);
    pack_adj<<<(BB * NN * NN) / (256 * 4), 256, 0, stream>>>(adj, adjm);
    transpose_split<<<dim3(FOUT / 32, FIN / 32, 1), tb, 0, stream>>>(W, WTh, WTl, FIN, FOUT);
    transpose_split<<<dim3(FOUT / 32, FOUT / 32, 1), tb, 0, stream>>>(a12, aTh, aTl, FOUT, FOUT);
    transpose_f32_bf16<<<dim3(FOUT / 32, FIN / 32, 1), tb, 0, stream>>>(W1, W1T, FIN, FOUT, 0, 0);
    transpose_f32_bf16<<<dim3(FOUT / 32, FIN / 32, 1), tb, 0, stream>>>(W2, W2T, FIN, FOUT, 0, 0);
    transpose_f32_bf16<<<dim3(FIN / 32, NN / 32, BB), tb, 0, stream>>>(
        feat, featT, NN, FIN, (long)NN * FIN, (long)FIN * NN);
    // h = feat @ W   (split precision)
    gemm_bt_split<<<dim3(BB * NN / 128, FOUT / 128, 1), 256, 0, stream>>>(
        fh, fl, WTh, WTl, hh, hl, nullptr, FOUT, FIN);
    // Ay = h @ a2
    ay_kernel<<<BB * NN / 4, 256, 0, stream>>>(hh, hl, a2, Ay);
    // q = h @ a12 + a1   (folds Ax[j] into q.h)
    gemm_bt_split<<<dim3(BB * NN / 128, FOUT / 128, 1), 256, 0, stream>>>(
        hh, hl, aTh, aTl, qh, ql, a1, FOUT, FOUT);
    // attention: scores+P~ -> merge -> fixup -> PV  (single group, all 8 batches)
    pass_score<<<dim3(NN / 64, 4, BB), 256, 0, stream>>>(
        qh, ql, hh, hl, adjm, Ay, mpm, mpl, P);
    ml_merge<<<(BB * NN) / 256, 256, 0, stream>>>(mpm, mpl, mlfin);
    fixup_p<<<dim3(NN, BB, 1), 256, 0, stream>>>(P, mpm, mlfin);
    gemm_bt<<<dim3(NN / 128, FIN / 128, BB), 256, 0, stream>>>(
        P, featT, fagg, FIN, NN, (long)NN * NN, (long)FIN * NN, (long)NN * FIN);
    // h1 = feat @ W1 ; h2 = fagg @ W2
    gemm_bt<<<dim3(BB * NN / 128, FOUT / 128, 1), 256, 0, stream>>>(
        fh, W1T, h1, FOUT, FIN, 0, 0, 0);
    gemm_bt<<<dim3(BB * NN / 128, FOUT / 128, 1), 256, 0, stream>>>(
        fagg, W2T, h2, FOUT, FIN, 0, 0, 0);
    // e1 = feat @ Lw^T ; e2 = fagg @ Rw^T
    e_kernel<<<BB * NN / 4, 256, 0, stream>>>(fh, Lw, e1);
    e_kernel<<<BB * NN / 4, 256, 0, stream>>>(fagg, Rw, e2);
    // out = h1 + h2 + e1.Bw.e2
    final_kernel<<<BB * NN, FOUT, 0, stream>>>(out, h1, h2, e1, e2, Bw);
}